// Round 8
// baseline (177.482 us; speedup 1.0000x reference)
//
#include <hip/hip_runtime.h>
#include <hip/hip_bf16.h>

#define NB 4
#define TT 2048
#define DD 1024
#define MM (NB*TT)

using f32x4  = __attribute__((ext_vector_type(4))) float;
using bf16x8 = __attribute__((ext_vector_type(8))) __bf16;
using u16x8  = __attribute__((ext_vector_type(8))) unsigned short;

__device__ __forceinline__ unsigned short f2b(float f) {
  __hip_bfloat16 h = __float2bfloat16(f);
  return *reinterpret_cast<unsigned short*>(&h);
}

__device__ __forceinline__ float b2f(unsigned short u) {
  __hip_bfloat16 h = *reinterpret_cast<__hip_bfloat16*>(&u);
  return __bfloat162float(h);
}

__device__ __forceinline__ void gld_lds16(const void* g, void* l) {
  __builtin_amdgcn_global_load_lds(
      (const __attribute__((address_space(1))) void*)g,
      (__attribute__((address_space(3))) void*)l, 16, 0, 0);
}

__device__ __forceinline__ void bar() {
  asm volatile("" ::: "memory");
  __builtin_amdgcn_s_barrier();
  asm volatile("" ::: "memory");
}

// ---------------- fp32 -> bf16 convert, all 4 tensors in one launch ----------------
__global__ void k_cvt4(const float* __restrict__ x,  const float* __restrict__ wq,
                       const float* __restrict__ wk, const float* __restrict__ wv,
                       unsigned short* __restrict__ xb, unsigned short* __restrict__ wqb,
                       unsigned short* __restrict__ wkb, unsigned short* __restrict__ wvb) {
  const int nx = MM*DD/4, nw = DD*DD/4;
  const int ntot = nx + 3*nw;
  int i = blockIdx.x * blockDim.x + threadIdx.x;
  int stride = gridDim.x * blockDim.x;
  for (; i < ntot; i += stride) {
    const float* s; unsigned short* d; int j;
    if (i < nx)            { s = x;  d = xb;  j = i; }
    else if (i < nx + nw)  { s = wq; d = wqb; j = i - nx; }
    else if (i < nx + 2*nw){ s = wk; d = wkb; j = i - nx - nw; }
    else                   { s = wv; d = wvb; j = i - nx - 2*nw; }
    float4 v = reinterpret_cast<const float4*>(s)[j];
    ushort4 o;
    o.x = f2b(v.x); o.y = f2b(v.y); o.z = f2b(v.z); o.w = f2b(v.w);
    reinterpret_cast<ushort4*>(d)[j] = o;
  }
}

// ---------------- QKV: 256x256, BK=64, m201-template-exact 8-phase ----------------
// 8 waves (2M x 4N); wave owns 128x64 of C = 8 m-frags x 4 n-frags.
// LDS 128KB: {A,B} x [2 slot][2 half][128 rows][128 B]; swizzle byte^=((row&7)<<4)
// via pre-swizzled global source (linear gload_lds dest) + swizzled ds_read
// (r7-verified conflict-free pair).
// Per K-tile, 4 phases; each: {reads for THIS phase's 16 MFMA} {stage} bar
// lgkmcnt(0) sched_barrier setprio MFMA x16 setprio bar.
// Read split (template): ph1 afL8+bfL4 | ph2 afU8 | ph3 bfR4 | ph4 none.
// Stages: Bh1(t+1)@ph1 -> S^1; Ah0(t+2)@ph3 -> S; Ah1+Bh0(t+2)@ph4 -> S.
// vmcnt(6)@ph4 only (drains tile t+1's 4 units; t+2's 3 units stay in flight).
__launch_bounds__(512, 2)
__global__ void k_qkv8(const unsigned short* __restrict__ xb,
                       const unsigned short* __restrict__ wqb,
                       const unsigned short* __restrict__ wkb,
                       const unsigned short* __restrict__ wvb,
                       unsigned short* __restrict__ Qb,
                       unsigned short* __restrict__ Kb,
                       unsigned short* __restrict__ Vt) {
  __shared__ __align__(16) char Lds[131072];
  const int tid = threadIdx.x;
  const int l = tid & 63, wid = tid >> 6;
  const int l15 = l & 15, l4 = l >> 4;
  const int wm = wid >> 2, wn = wid & 3;
  const int z = blockIdx.z;
  const unsigned short* W = (z == 0) ? wqb : (z == 1) ? wkb : wvb;
  const size_t m0 = (size_t)blockIdx.x * 256;
  const size_t n0 = (size_t)blockIdx.y * 256;

  // staging: linear LDS dest byte d -> pre-swizzled global (row, colbyte)
  int srow[2], scb[2];
  #pragma unroll
  for (int j = 0; j < 2; ++j) {
    int d  = (j*512 + tid) * 16;
    int sd = d ^ (((d >> 7) & 7) << 4);    // involution, row unchanged
    srow[j] = sd >> 7;
    scb[j]  = sd & 127;
  }
  const char* pA[2][2]; const char* pB[2][2];
  #pragma unroll
  for (int h = 0; h < 2; ++h)
    #pragma unroll
    for (int j = 0; j < 2; ++j) {
      pA[h][j] = (const char*)xb + ((m0 + h*128 + srow[j]) * DD) * 2 + scb[j];
      pB[h][j] = (const char*)W  + ((n0 + h*128 + srow[j]) * DD) * 2 + scb[j];
    }
  char* ldsA = Lds;
  char* ldsB = Lds + 65536;

#define STG(p, ldsr, slot, half, kt) do {                                         \
    gld_lds16(p[half][0] + (size_t)(kt)*128,                                      \
              (ldsr) + (slot)*32768 + (half)*16384 + wid*1024);                   \
    gld_lds16(p[half][1] + (size_t)(kt)*128,                                      \
              (ldsr) + (slot)*32768 + (half)*16384 + 8192 + wid*1024);            \
  } while (0)

#define SWZ(x) ((x) ^ ((((x) >> 7) & 7) << 4))
#define KTQ 16
  // prologue: tile0 fully (4 units) + tile1 partial (3 units); vmcnt(6) -> tile0 landed
  STG(pA, ldsA, 0, 0, 0);
  STG(pA, ldsA, 0, 1, 0);
  STG(pB, ldsB, 0, 0, 0);
  STG(pB, ldsB, 0, 1, 0);
  STG(pA, ldsA, 1, 0, 1);
  STG(pA, ldsA, 1, 1, 1);
  STG(pB, ldsB, 1, 0, 1);
  asm volatile("s_waitcnt vmcnt(6)" ::: "memory");
  bar();

  f32x4 acc[8][4] = {};
  bf16x8 afL[4][2], afU[4][2], bfL[2][2], bfR[2][2];

#define TILE(t, S) do {                                                           \
    const int tn = ((t)+1 < KTQ) ? (t)+1 : 0;                                     \
    const int t2 = ((t)+2 < KTQ) ? (t)+2 : 0;                                     \
    /* ---- ph1: reads afL(8)+bfL(4); stage Bh1(t+1)->S^1; MFMA q1 mLxnL ---- */  \
    _Pragma("unroll") for (int m = 0; m < 4; ++m)                                 \
      _Pragma("unroll") for (int kk = 0; kk < 2; ++kk) {                          \
        int lg = (m*16 + l15)*128 + (kk*64 + l4*16);                              \
        afL[m][kk] = *(const bf16x8*)(ldsA + (S)*32768 + wm*16384 + SWZ(lg)); }   \
    _Pragma("unroll") for (int n = 0; n < 2; ++n)                                 \
      _Pragma("unroll") for (int kk = 0; kk < 2; ++kk) {                          \
        int lg = ((wn&1)*64 + n*16 + l15)*128 + (kk*64 + l4*16);                  \
        bfL[n][kk] = *(const bf16x8*)(ldsB + (S)*32768 + (wn>>1)*16384 + SWZ(lg)); } \
    STG(pB, ldsB, (S)^1, 1, tn);                                                  \
    bar();                                                                        \
    asm volatile("s_waitcnt lgkmcnt(0)" ::: "memory");                            \
    __builtin_amdgcn_sched_barrier(0);                                            \
    __builtin_amdgcn_s_setprio(1);                                                \
    _Pragma("unroll") for (int m = 0; m < 4; ++m)                                 \
      _Pragma("unroll") for (int n = 0; n < 2; ++n)                               \
        _Pragma("unroll") for (int kk = 0; kk < 2; ++kk)                          \
          acc[m][n] = __builtin_amdgcn_mfma_f32_16x16x32_bf16(afL[m][kk], bfL[n][kk], acc[m][n], 0,0,0); \
    __builtin_amdgcn_s_setprio(0);                                                \
    bar();                                                                        \
    /* ---- ph2: reads afU(8); no stage; MFMA q2 mUxnL ---- */                    \
    _Pragma("unroll") for (int m = 0; m < 4; ++m)                                 \
      _Pragma("unroll") for (int kk = 0; kk < 2; ++kk) {                          \
        int lg = ((m+4)*16 + l15)*128 + (kk*64 + l4*16);                          \
        afU[m][kk] = *(const bf16x8*)(ldsA + (S)*32768 + wm*16384 + SWZ(lg)); }   \
    bar();                                                                        \
    asm volatile("s_waitcnt lgkmcnt(0)" ::: "memory");                            \
    __builtin_amdgcn_sched_barrier(0);                                            \
    __builtin_amdgcn_s_setprio(1);                                                \
    _Pragma("unroll") for (int m = 0; m < 4; ++m)                                 \
      _Pragma("unroll") for (int n = 0; n < 2; ++n)                               \
        _Pragma("unroll") for (int kk = 0; kk < 2; ++kk)                          \
          acc[m+4][n] = __builtin_amdgcn_mfma_f32_16x16x32_bf16(afU[m][kk], bfL[n][kk], acc[m+4][n], 0,0,0); \
    __builtin_amdgcn_s_setprio(0);                                                \
    bar();                                                                        \
    /* ---- ph3: reads bfR(4); stage Ah0(t+2)->S; MFMA q3 mUxnR ---- */           \
    _Pragma("unroll") for (int n = 0; n < 2; ++n)                                 \
      _Pragma("unroll") for (int kk = 0; kk < 2; ++kk) {                          \
        int lg = ((wn&1)*64 + (n+2)*16 + l15)*128 + (kk*64 + l4*16);              \
        bfR[n][kk] = *(const bf16x8*)(ldsB + (S)*32768 + (wn>>1)*16384 + SWZ(lg)); } \
    STG(pA, ldsA, S, 0, t2);                                                      \
    bar();                                                                        \
    asm volatile("s_waitcnt lgkmcnt(0)" ::: "memory");                            \
    __builtin_amdgcn_sched_barrier(0);                                            \
    __builtin_amdgcn_s_setprio(1);                                                \
    _Pragma("unroll") for (int m = 0; m < 4; ++m)                                 \
      _Pragma("unroll") for (int n = 0; n < 2; ++n)                               \
        _Pragma("unroll") for (int kk = 0; kk < 2; ++kk)                          \
          acc[m+4][n+2] = __builtin_amdgcn_mfma_f32_16x16x32_bf16(afU[m][kk], bfR[n][kk], acc[m+4][n+2], 0,0,0); \
    __builtin_amdgcn_s_setprio(0);                                                \
    bar();                                                                        \
    /* ---- ph4: stage Ah1+Bh0(t+2)->S; vmcnt(6); MFMA q4 mLxnR (regs) ---- */    \
    STG(pA, ldsA, S, 1, t2);                                                      \
    STG(pB, ldsB, S, 0, t2);                                                      \
    asm volatile("s_waitcnt vmcnt(6)" ::: "memory");                              \
    bar();                                                                        \
    __builtin_amdgcn_s_setprio(1);                                                \
    _Pragma("unroll") for (int m = 0; m < 4; ++m)                                 \
      _Pragma("unroll") for (int n = 0; n < 2; ++n)                               \
        _Pragma("unroll") for (int kk = 0; kk < 2; ++kk)                          \
          acc[m][n+2] = __builtin_amdgcn_mfma_f32_16x16x32_bf16(afL[m][kk], bfR[n][kk], acc[m][n+2], 0,0,0); \
    __builtin_amdgcn_s_setprio(0);                                                \
    bar();                                                                        \
  } while (0)

  for (int tp = 0; tp < KTQ; tp += 2) {
    TILE(tp, 0);
    TILE(tp + 1, 1);
  }
#undef TILE
#undef STG
#undef SWZ
  asm volatile("s_waitcnt vmcnt(0)" ::: "memory");

  // ---- epilogue: C-write (row = l4*4+r, col = l15) ----
  if (z < 2) {
    unsigned short* out = (z == 0) ? Qb : Kb;
    #pragma unroll
    for (int m = 0; m < 8; ++m)
      #pragma unroll
      for (int n = 0; n < 4; ++n)
        #pragma unroll
        for (int r = 0; r < 4; ++r) {
          size_t row = m0 + wm*128 + m*16 + l4*4 + r;
          size_t col = n0 + wn*64  + n*16 + l15;
          out[row * DD + col] = f2b(acc[m][n][r]);
        }
  } else {
    #pragma unroll
    for (int m = 0; m < 8; ++m)
      #pragma unroll
      for (int n = 0; n < 4; ++n)
        #pragma unroll
        for (int r = 0; r < 4; ++r) {
          size_t row = m0 + wm*128 + m*16 + l4*4 + r;
          size_t col = n0 + wn*64  + n*16 + l15;
          size_t b = row >> 11, t = row & (TT - 1);
          Vt[(b * DD + col) * TT + t] = f2b(acc[m][n][r]);   // Vt[b][d][t]
        }
  }
}

// ---------------- S = scale * Q K^T (causal tiles), BK=64 + swizzle (r7 structure) ----
__launch_bounds__(256)
__global__ void k_scores(const unsigned short* __restrict__ Qb,
                         const unsigned short* __restrict__ Kb,
                         unsigned short* __restrict__ S) {
  __shared__ __align__(16) unsigned short As[128*64];
  __shared__ __align__(16) unsigned short Bs[128*64];
  const int tid = threadIdx.x;
  const int l = tid & 63, wid = tid >> 6;
  const int l15 = l & 15, l4 = l >> 4;
  const int wr = (wid >> 1) * 64, wc = (wid & 1) * 64;

  const int bid = blockIdx.x;
  const int swz = (bid & 7) * 68 + (bid >> 3);   // bijective, 544 = 8*68
  const int b = swz / 136;
  int t = swz % 136;
  int qi = 0;
  while ((qi + 1) * (qi + 2) / 2 <= t) qi++;
  const int ki = t - qi * (qi + 1) / 2;

  const size_t arow0 = (size_t)b * TT + qi * 128;
  const size_t brow0 = (size_t)b * TT + ki * 128;

  const int srow = wid * 8 + (l >> 3);
  const int scol = 8 * ((l & 7) ^ (l >> 3));
  const unsigned short* Ap = Qb + (arow0 + srow) * DD + scol;
  const unsigned short* Bp = Kb + (brow0 + srow) * DD + scol;
  unsigned short* AsW = &As[wid * 512];
  unsigned short* BsW = &Bs[wid * 512];

  f32x4 acc[4][4] = {};

  for (int k0 = 0; k0 < DD; k0 += 64) {
    __syncthreads();
    #pragma unroll
    for (int u = 0; u < 4; ++u) {
      gld_lds16(Ap + (size_t)u*32*DD + k0, AsW + u*2048);
      gld_lds16(Bp + (size_t)u*32*DD + k0, BsW + u*2048);
    }
    __syncthreads();
    #pragma unroll
    for (int kk = 0; kk < 2; ++kk) {
      bf16x8 af[4], bfr[4];
      #pragma unroll
      for (int mi = 0; mi < 4; ++mi) {
        int ro = wr + mi*16 + l15;
        int off = ro*128 + ((kk*64 + l4*16) ^ ((ro & 7) << 4));
        af[mi] = *reinterpret_cast<const bf16x8*>((const char*)As + off);
      }
      #pragma unroll
      for (int ni = 0; ni < 4; ++ni) {
        int ro = wc + ni*16 + l15;
        int off = ro*128 + ((kk*64 + l4*16) ^ ((ro & 7) << 4));
        bfr[ni] = *reinterpret_cast<const bf16x8*>((const char*)Bs + off);
      }
      #pragma unroll
      for (int mi = 0; mi < 4; ++mi)
        #pragma unroll
        for (int ni = 0; ni < 4; ++ni)
          acc[mi][ni] = __builtin_amdgcn_mfma_f32_16x16x32_bf16(af[mi], bfr[ni], acc[mi][ni], 0, 0, 0);
    }
  }

  const float scale = 0.03125f;
  #pragma unroll
  for (int mi = 0; mi < 4; ++mi)
    #pragma unroll
    for (int ni = 0; ni < 4; ++ni)
      #pragma unroll
      for (int r = 0; r < 4; ++r) {
        int row = wr + mi*16 + l4*4 + r;
        int col = wc + ni*16 + l15;
        int gq = qi*128 + row, gk = ki*128 + col;
        float v = (gk > gq) ? -1e30f : acc[mi][ni][r] * scale;
        S[((size_t)b * TT + gq) * TT + gk] = f2b(v);
      }
}

// ---------------- rowwise softmax in place ----------------
__launch_bounds__(256)
__global__ void k_softmax(unsigned short* __restrict__ S, float* __restrict__ rl) {
  const int tid = threadIdx.x;
  const int w = tid >> 6, l = tid & 63;
  const int row = blockIdx.x * 4 + w;
  const int b = row >> 11, q = row & (TT - 1);
  unsigned short* Srow = S + ((size_t)b * TT + q) * TT;
  const int width = ((q >> 7) + 1) << 7;

  float v[4][8];
  bool has[4];
  float mx = -1e30f;
  #pragma unroll
  for (int c = 0; c < 4; ++c) {
    const int off = c * 512 + l * 8;
    has[c] = off < width;
    if (has[c]) {
      u16x8 u = *reinterpret_cast<const u16x8*>(&Srow[off]);
      #pragma unroll
      for (int j = 0; j < 8; ++j) { v[c][j] = b2f(u[j]); mx = fmaxf(mx, v[c][j]); }
    }
  }
  #pragma unroll
  for (int mm = 1; mm < 64; mm <<= 1) mx = fmaxf(mx, __shfl_xor(mx, mm));

  float s = 0.f;
  #pragma unroll
  for (int c = 0; c < 4; ++c) {
    if (has[c]) {
      u16x8 u;
      #pragma unroll
      for (int j = 0; j < 8; ++j) {
        float p = __expf(v[c][j] - mx);
        s += p;
        u[j] = f2b(p);
      }
      *reinterpret_cast<u16x8*>(&Srow[c * 512 + l * 8]) = u;
    }
  }
  #pragma unroll
  for (int mm = 1; mm < 64; mm <<= 1) s += __shfl_xor(s, mm);
  if (l == 0) rl[row] = 1.0f / s;
}

// ---------------- O = (P Vt^T) * rl, BK=64 + swizzle (r7 structure) ----------------
__launch_bounds__(256)
__global__ void k_pv(const unsigned short* __restrict__ P,
                     const unsigned short* __restrict__ Vt,
                     const float* __restrict__ rl,
                     float* __restrict__ O) {
  __shared__ __align__(16) unsigned short As[128*64];
  __shared__ __align__(16) unsigned short Bs[128*64];
  const int tid = threadIdx.x;
  const int l = tid & 63, wid = tid >> 6;
  const int l15 = l & 15, l4 = l >> 4;
  const int wr = (wid >> 1) * 64, wc = (wid & 1) * 64;

  const int qi = 15 - (blockIdx.x >> 5);       // heaviest first
  const int di = (blockIdx.x >> 2) & 7;
  const int b  = blockIdx.x & 3;
  const int KEXT = (qi + 1) * 128;

  const int srow = wid * 8 + (l >> 3);
  const int scol = 8 * ((l & 7) ^ (l >> 3));
  const unsigned short* Ap = P  + ((size_t)b * TT + qi * 128 + srow) * TT + scol;
  const unsigned short* Bp = Vt + ((size_t)b * DD + di * 128 + srow) * TT + scol;
  unsigned short* AsW = &As[wid * 512];
  unsigned short* BsW = &Bs[wid * 512];

  f32x4 acc[4][4] = {};

  for (int k0 = 0; k0 < KEXT; k0 += 64) {
    __syncthreads();
    #pragma unroll
    for (int u = 0; u < 4; ++u) {
      gld_lds16(Ap + (size_t)u*32*TT + k0, AsW + u*2048);
      gld_lds16(Bp + (size_t)u*32*TT + k0, BsW + u*2048);
    }
    __syncthreads();
    #pragma unroll
    for (int kk = 0; kk < 2; ++kk) {
      bf16x8 af[4], bfr[4];
      #pragma unroll
      for (int mi = 0; mi < 4; ++mi) {
        int ro = wr + mi*16 + l15;
        int off = ro*128 + ((kk*64 + l4*16) ^ ((ro & 7) << 4));
        af[mi] = *reinterpret_cast<const bf16x8*>((const char*)As + off);
      }
      #pragma unroll
      for (int ni = 0; ni < 4; ++ni) {
        int ro = wc + ni*16 + l15;
        int off = ro*128 + ((kk*64 + l4*16) ^ ((ro & 7) << 4));
        bfr[ni] = *reinterpret_cast<const bf16x8*>((const char*)Bs + off);
      }
      #pragma unroll
      for (int mi = 0; mi < 4; ++mi)
        #pragma unroll
        for (int ni = 0; ni < 4; ++ni)
          acc[mi][ni] = __builtin_amdgcn_mfma_f32_16x16x32_bf16(af[mi], bfr[ni], acc[mi][ni], 0, 0, 0);
    }
  }

  #pragma unroll
  for (int mi = 0; mi < 4; ++mi)
    #pragma unroll
    for (int ni = 0; ni < 4; ++ni)
      #pragma unroll
      for (int r = 0; r < 4; ++r) {
        int row = wr + mi*16 + l4*4 + r;
        int col = wc + ni*16 + l15;
        size_t q = (size_t)qi * 128 + row;
        O[((size_t)b * TT + q) * DD + di * 128 + col] =
            acc[mi][ni][r] * rl[(size_t)b * TT + q];
      }
}

extern "C" void kernel_launch(void* const* d_in, const int* in_sizes, int n_in,
                              void* d_out, int out_size, void* d_ws, size_t ws_size,
                              hipStream_t stream) {
  const float* x  = (const float*)d_in[0];
  const float* wq = (const float*)d_in[1];
  const float* wk = (const float*)d_in[2];
  const float* wv = (const float*)d_in[3];
  unsigned short* ws  = (unsigned short*)d_ws;
  unsigned short* Qb  = ws;
  unsigned short* Kb  = Qb + (size_t)MM * DD;
  unsigned short* Vt  = Kb + (size_t)MM * DD;
  unsigned short* Sb  = Vt + (size_t)MM * DD;        // NB*TT*TT elems
  unsigned short* xb  = Sb;                          // alias (dead after k_qkv8)
  unsigned short* wqb = xb + (size_t)MM * DD;
  unsigned short* wkb = wqb + (size_t)DD * DD;
  unsigned short* wvb = wkb + (size_t)DD * DD;
  float* rl = (float*)(Sb + (size_t)NB * TT * TT);
  float* out = (float*)d_out;

  k_cvt4<<<2048, 256, 0, stream>>>(x, wq, wk, wv, xb, wqb, wkb, wvb);
  k_qkv8<<<dim3(32, 4, 3), 512, 0, stream>>>(xb, wqb, wkb, wvb, Qb, Kb, Vt);
  k_scores<<<544, 256, 0, stream>>>(Qb, Kb, Sb);
  k_softmax<<<MM/4, 256, 0, stream>>>(Sb, rl);
  k_pv<<<512, 256, 0, stream>>>(Sb, Vt, rl, out);
}

// Round 9
// 158.625 us; speedup vs baseline: 1.1189x; 1.1189x over previous
//
#include <hip/hip_runtime.h>
#include <hip/hip_bf16.h>

#define NB 4
#define TT 2048
#define DD 1024
#define MM (NB*TT)

using f32x4  = __attribute__((ext_vector_type(4))) float;
using bf16x8 = __attribute__((ext_vector_type(8))) __bf16;
using u16x8  = __attribute__((ext_vector_type(8))) unsigned short;

__device__ __forceinline__ unsigned short f2b(float f) {
  __hip_bfloat16 h = __float2bfloat16(f);
  return *reinterpret_cast<unsigned short*>(&h);
}

__device__ __forceinline__ float b2f(unsigned short u) {
  __hip_bfloat16 h = *reinterpret_cast<__hip_bfloat16*>(&u);
  return __bfloat162float(h);
}

__device__ __forceinline__ void gld_lds16(const void* g, void* l) {
  __builtin_amdgcn_global_load_lds(
      (const __attribute__((address_space(1))) void*)g,
      (__attribute__((address_space(3))) void*)l, 16, 0, 0);
}

// ---------------- fp32 -> bf16 convert, all 4 tensors in one launch ----------------
__global__ void k_cvt4(const float* __restrict__ x,  const float* __restrict__ wq,
                       const float* __restrict__ wk, const float* __restrict__ wv,
                       unsigned short* __restrict__ xb, unsigned short* __restrict__ wqb,
                       unsigned short* __restrict__ wkb, unsigned short* __restrict__ wvb) {
  const int nx = MM*DD/4, nw = DD*DD/4;
  const int ntot = nx + 3*nw;
  int i = blockIdx.x * blockDim.x + threadIdx.x;
  int stride = gridDim.x * blockDim.x;
  for (; i < ntot; i += stride) {
    const float* s; unsigned short* d; int j;
    if (i < nx)            { s = x;  d = xb;  j = i; }
    else if (i < nx + nw)  { s = wq; d = wqb; j = i - nx; }
    else if (i < nx + 2*nw){ s = wk; d = wkb; j = i - nx - nw; }
    else                   { s = wv; d = wvb; j = i - nx - 2*nw; }
    float4 v = reinterpret_cast<const float4*>(s)[j];
    ushort4 o;
    o.x = f2b(v.x); o.y = f2b(v.y); o.z = f2b(v.z); o.w = f2b(v.w);
    reinterpret_cast<ushort4*>(d)[j] = o;
  }
}

// ---------------- QKV projection GEMM: Y = X(M,K) * W(N,K)^T ----------------
// r7-proven: 2-phase, 128x128 tile, BK=64, 4 waves 2x2, conflict-free swizzle
// (byte ^= ((row&7)<<4) via pre-swizzled global source + swizzled ds_read).
// 74.9 us / 688 TF / MfmaUtil 27.7 / conflicts 0.  z=2 (V) stores Vt[b][d][t].
__launch_bounds__(256)
__global__ void k_qkv(const unsigned short* __restrict__ xb,
                      const unsigned short* __restrict__ wqb,
                      const unsigned short* __restrict__ wkb,
                      const unsigned short* __restrict__ wvb,
                      unsigned short* __restrict__ Qb,
                      unsigned short* __restrict__ Kb,
                      unsigned short* __restrict__ Vt) {
  __shared__ __align__(16) unsigned short As[128*64];   // 16 KB
  __shared__ __align__(16) unsigned short Bs[128*64];   // 16 KB
  const int tid = threadIdx.x;
  const int l = tid & 63, wid = tid >> 6;
  const int z = blockIdx.z;
  const unsigned short* W = (z == 0) ? wqb : (z == 1) ? wkb : wvb;
  unsigned short* out = (z == 0) ? Qb : (z == 1) ? Kb : Vt;
  const long m0 = (long)blockIdx.x * 128;
  const long n0 = (long)blockIdx.y * 128;
  const int l15 = l & 15, l4 = l >> 4;
  const int wr = (wid >> 1) * 64, wc = (wid & 1) * 64;

  // staging: thread t=64w+l -> linear LDS byte w*1024 + l*16 (per 32-row unit);
  // global source PRE-SWIZZLED: row = u*32 + w*8 + (l>>3), colE = 8*((l&7)^(l>>3))
  const int srow = wid * 8 + (l >> 3);
  const int scol = 8 * ((l & 7) ^ (l >> 3));
  const unsigned short* Ap = xb + (m0 + srow) * DD + scol;
  const unsigned short* Wp = W  + (n0 + srow) * DD + scol;
  unsigned short* AsW = &As[wid * 512];
  unsigned short* BsW = &Bs[wid * 512];

  f32x4 acc[4][4] = {};

  for (int k0 = 0; k0 < DD; k0 += 64) {
    __syncthreads();                       // prev-iter frag reads done
    #pragma unroll
    for (int u = 0; u < 4; ++u) {
      gld_lds16(Ap + (size_t)u*32*DD + k0, AsW + u*2048);
      gld_lds16(Wp + (size_t)u*32*DD + k0, BsW + u*2048);
    }
    __syncthreads();                       // drains vmcnt -> tiles ready
    #pragma unroll
    for (int kk = 0; kk < 2; ++kk) {
      bf16x8 af[4], bfr[4];
      #pragma unroll
      for (int mi = 0; mi < 4; ++mi) {
        int ro = wr + mi*16 + l15;
        int off = ro*128 + ((kk*64 + l4*16) ^ ((ro & 7) << 4));   // bytes, swizzled
        af[mi] = *reinterpret_cast<const bf16x8*>((const char*)As + off);
      }
      #pragma unroll
      for (int ni = 0; ni < 4; ++ni) {
        int ro = wc + ni*16 + l15;
        int off = ro*128 + ((kk*64 + l4*16) ^ ((ro & 7) << 4));
        bfr[ni] = *reinterpret_cast<const bf16x8*>((const char*)Bs + off);
      }
      #pragma unroll
      for (int mi = 0; mi < 4; ++mi)
        #pragma unroll
        for (int ni = 0; ni < 4; ++ni)
          acc[mi][ni] = __builtin_amdgcn_mfma_f32_16x16x32_bf16(af[mi], bfr[ni], acc[mi][ni], 0, 0, 0);
    }
  }

  // C/D layout: row = (l>>4)*4 + r, col = l&15
  if (z < 2) {
    #pragma unroll
    for (int mi = 0; mi < 4; ++mi)
      #pragma unroll
      for (int ni = 0; ni < 4; ++ni)
        #pragma unroll
        for (int r = 0; r < 4; ++r) {
          long row = m0 + wr + mi*16 + l4*4 + r;
          long col = n0 + wc + ni*16 + l15;
          out[row * DD + col] = f2b(acc[mi][ni][r]);
        }
  } else {
    #pragma unroll
    for (int mi = 0; mi < 4; ++mi)
      #pragma unroll
      for (int ni = 0; ni < 4; ++ni)
        #pragma unroll
        for (int r = 0; r < 4; ++r) {
          long row = m0 + wr + mi*16 + l4*4 + r;
          long col = n0 + wc + ni*16 + l15;
          long b = row >> 11, t = row & (TT - 1);
          out[(b * DD + col) * TT + t] = f2b(acc[mi][ni][r]);   // Vt[b][d][t]
        }
  }
}

// ---------------- S = scale * Q K^T (causal tiles), BK=64 + swizzle ----------------
__launch_bounds__(256)
__global__ void k_scores(const unsigned short* __restrict__ Qb,
                         const unsigned short* __restrict__ Kb,
                         unsigned short* __restrict__ S) {
  __shared__ __align__(16) unsigned short As[128*64];
  __shared__ __align__(16) unsigned short Bs[128*64];
  const int tid = threadIdx.x;
  const int l = tid & 63, wid = tid >> 6;
  const int l15 = l & 15, l4 = l >> 4;
  const int wr = (wid >> 1) * 64, wc = (wid & 1) * 64;

  const int bid = blockIdx.x;
  const int swz = (bid & 7) * 68 + (bid >> 3);   // bijective XCD swizzle, 544 = 8*68
  const int b = swz / 136;
  int t = swz % 136;
  int qi = 0;
  while ((qi + 1) * (qi + 2) / 2 <= t) qi++;
  const int ki = t - qi * (qi + 1) / 2;

  const size_t arow0 = (size_t)b * TT + qi * 128;
  const size_t brow0 = (size_t)b * TT + ki * 128;

  const int srow = wid * 8 + (l >> 3);
  const int scol = 8 * ((l & 7) ^ (l >> 3));
  const unsigned short* Ap = Qb + (arow0 + srow) * DD + scol;
  const unsigned short* Bp = Kb + (brow0 + srow) * DD + scol;
  unsigned short* AsW = &As[wid * 512];
  unsigned short* BsW = &Bs[wid * 512];

  f32x4 acc[4][4] = {};

  for (int k0 = 0; k0 < DD; k0 += 64) {
    __syncthreads();
    #pragma unroll
    for (int u = 0; u < 4; ++u) {
      gld_lds16(Ap + (size_t)u*32*DD + k0, AsW + u*2048);
      gld_lds16(Bp + (size_t)u*32*DD + k0, BsW + u*2048);
    }
    __syncthreads();
    #pragma unroll
    for (int kk = 0; kk < 2; ++kk) {
      bf16x8 af[4], bfr[4];
      #pragma unroll
      for (int mi = 0; mi < 4; ++mi) {
        int ro = wr + mi*16 + l15;
        int off = ro*128 + ((kk*64 + l4*16) ^ ((ro & 7) << 4));
        af[mi] = *reinterpret_cast<const bf16x8*>((const char*)As + off);
      }
      #pragma unroll
      for (int ni = 0; ni < 4; ++ni) {
        int ro = wc + ni*16 + l15;
        int off = ro*128 + ((kk*64 + l4*16) ^ ((ro & 7) << 4));
        bfr[ni] = *reinterpret_cast<const bf16x8*>((const char*)Bs + off);
      }
      #pragma unroll
      for (int mi = 0; mi < 4; ++mi)
        #pragma unroll
        for (int ni = 0; ni < 4; ++ni)
          acc[mi][ni] = __builtin_amdgcn_mfma_f32_16x16x32_bf16(af[mi], bfr[ni], acc[mi][ni], 0, 0, 0);
    }
  }

  const float scale = 0.03125f;
  #pragma unroll
  for (int mi = 0; mi < 4; ++mi)
    #pragma unroll
    for (int ni = 0; ni < 4; ++ni)
      #pragma unroll
      for (int r = 0; r < 4; ++r) {
        int row = wr + mi*16 + l4*4 + r;
        int col = wc + ni*16 + l15;
        int gq = qi*128 + row, gk = ki*128 + col;
        float v = (gk > gq) ? -1e30f : acc[mi][ni][r] * scale;
        S[((size_t)b * TT + gq) * TT + gk] = f2b(v);
      }
}

// ---------------- rowwise softmax in place ----------------
__launch_bounds__(256)
__global__ void k_softmax(unsigned short* __restrict__ S, float* __restrict__ rl) {
  const int tid = threadIdx.x;
  const int w = tid >> 6, l = tid & 63;
  const int row = blockIdx.x * 4 + w;
  const int b = row >> 11, q = row & (TT - 1);
  unsigned short* Srow = S + ((size_t)b * TT + q) * TT;
  const int width = ((q >> 7) + 1) << 7;

  float v[4][8];
  bool has[4];
  float mx = -1e30f;
  #pragma unroll
  for (int c = 0; c < 4; ++c) {
    const int off = c * 512 + l * 8;
    has[c] = off < width;
    if (has[c]) {
      u16x8 u = *reinterpret_cast<const u16x8*>(&Srow[off]);
      #pragma unroll
      for (int j = 0; j < 8; ++j) { v[c][j] = b2f(u[j]); mx = fmaxf(mx, v[c][j]); }
    }
  }
  #pragma unroll
  for (int mm = 1; mm < 64; mm <<= 1) mx = fmaxf(mx, __shfl_xor(mx, mm));

  float s = 0.f;
  #pragma unroll
  for (int c = 0; c < 4; ++c) {
    if (has[c]) {
      u16x8 u;
      #pragma unroll
      for (int j = 0; j < 8; ++j) {
        float p = __expf(v[c][j] - mx);
        s += p;
        u[j] = f2b(p);
      }
      *reinterpret_cast<u16x8*>(&Srow[c * 512 + l * 8]) = u;
    }
  }
  #pragma unroll
  for (int mm = 1; mm < 64; mm <<= 1) s += __shfl_xor(s, mm);
  if (l == 0) rl[row] = 1.0f / s;
}

// ---------------- O = (P Vt^T) * rl, BK=64 + swizzle ----------------
__launch_bounds__(256)
__global__ void k_pv(const unsigned short* __restrict__ P,
                     const unsigned short* __restrict__ Vt,
                     const float* __restrict__ rl,
                     float* __restrict__ O) {
  __shared__ __align__(16) unsigned short As[128*64];
  __shared__ __align__(16) unsigned short Bs[128*64];
  const int tid = threadIdx.x;
  const int l = tid & 63, wid = tid >> 6;
  const int l15 = l & 15, l4 = l >> 4;
  const int wr = (wid >> 1) * 64, wc = (wid & 1) * 64;

  const int qi = 15 - (blockIdx.x >> 5);       // heaviest first
  const int di = (blockIdx.x >> 2) & 7;
  const int b  = blockIdx.x & 3;
  const int KEXT = (qi + 1) * 128;

  const int srow = wid * 8 + (l >> 3);
  const int scol = 8 * ((l & 7) ^ (l >> 3));
  const unsigned short* Ap = P  + ((size_t)b * TT + qi * 128 + srow) * TT + scol;
  const unsigned short* Bp = Vt + ((size_t)b * DD + di * 128 + srow) * TT + scol;
  unsigned short* AsW = &As[wid * 512];
  unsigned short* BsW = &Bs[wid * 512];

  f32x4 acc[4][4] = {};

  for (int k0 = 0; k0 < KEXT; k0 += 64) {
    __syncthreads();
    #pragma unroll
    for (int u = 0; u < 4; ++u) {
      gld_lds16(Ap + (size_t)u*32*TT + k0, AsW + u*2048);
      gld_lds16(Bp + (size_t)u*32*TT + k0, BsW + u*2048);
    }
    __syncthreads();
    #pragma unroll
    for (int kk = 0; kk < 2; ++kk) {
      bf16x8 af[4], bfr[4];
      #pragma unroll
      for (int mi = 0; mi < 4; ++mi) {
        int ro = wr + mi*16 + l15;
        int off = ro*128 + ((kk*64 + l4*16) ^ ((ro & 7) << 4));
        af[mi] = *reinterpret_cast<const bf16x8*>((const char*)As + off);
      }
      #pragma unroll
      for (int ni = 0; ni < 4; ++ni) {
        int ro = wc + ni*16 + l15;
        int off = ro*128 + ((kk*64 + l4*16) ^ ((ro & 7) << 4));
        bfr[ni] = *reinterpret_cast<const bf16x8*>((const char*)Bs + off);
      }
      #pragma unroll
      for (int mi = 0; mi < 4; ++mi)
        #pragma unroll
        for (int ni = 0; ni < 4; ++ni)
          acc[mi][ni] = __builtin_amdgcn_mfma_f32_16x16x32_bf16(af[mi], bfr[ni], acc[mi][ni], 0, 0, 0);
    }
  }

  #pragma unroll
  for (int mi = 0; mi < 4; ++mi)
    #pragma unroll
    for (int ni = 0; ni < 4; ++ni)
      #pragma unroll
      for (int r = 0; r < 4; ++r) {
        int row = wr + mi*16 + l4*4 + r;
        int col = wc + ni*16 + l15;
        size_t q = (size_t)qi * 128 + row;
        O[((size_t)b * TT + q) * DD + di * 128 + col] =
            acc[mi][ni][r] * rl[(size_t)b * TT + q];
      }
}

extern "C" void kernel_launch(void* const* d_in, const int* in_sizes, int n_in,
                              void* d_out, int out_size, void* d_ws, size_t ws_size,
                              hipStream_t stream) {
  const float* x  = (const float*)d_in[0];
  const float* wq = (const float*)d_in[1];
  const float* wk = (const float*)d_in[2];
  const float* wv = (const float*)d_in[3];
  unsigned short* ws  = (unsigned short*)d_ws;
  unsigned short* Qb  = ws;
  unsigned short* Kb  = Qb + (size_t)MM * DD;
  unsigned short* Vt  = Kb + (size_t)MM * DD;
  unsigned short* Sb  = Vt + (size_t)MM * DD;        // NB*TT*TT elems
  unsigned short* xb  = Sb;                          // alias (dead after k_qkv)
  unsigned short* wqb = xb + (size_t)MM * DD;
  unsigned short* wkb = wqb + (size_t)DD * DD;
  unsigned short* wvb = wkb + (size_t)DD * DD;
  float* rl = (float*)(Sb + (size_t)NB * TT * TT);
  float* out = (float*)d_out;

  k_cvt4<<<2048, 256, 0, stream>>>(x, wq, wk, wv, xb, wqb, wkb, wvb);
  k_qkv<<<dim3(MM/128, DD/128, 3), 256, 0, stream>>>(xb, wqb, wkb, wvb, Qb, Kb, Vt);
  k_scores<<<544, 256, 0, stream>>>(Qb, Kb, Sb);
  k_softmax<<<MM/4, 256, 0, stream>>>(Sb, rl);
  k_pv<<<512, 256, 0, stream>>>(Sb, Vt, rl, out);
}

// Round 10
// 152.960 us; speedup vs baseline: 1.1603x; 1.0370x over previous
//
#include <hip/hip_runtime.h>
#include <hip/hip_bf16.h>

#define NB 4
#define TT 2048
#define DD 1024
#define MM (NB*TT)

using f32x4  = __attribute__((ext_vector_type(4))) float;
using bf16x8 = __attribute__((ext_vector_type(8))) __bf16;
using u16x8  = __attribute__((ext_vector_type(8))) unsigned short;

__device__ __forceinline__ unsigned short f2b(float f) {
  __hip_bfloat16 h = __float2bfloat16(f);
  return *reinterpret_cast<unsigned short*>(&h);
}

__device__ __forceinline__ float b2f(unsigned short u) {
  __hip_bfloat16 h = *reinterpret_cast<__hip_bfloat16*>(&u);
  return __bfloat162float(h);
}

__device__ __forceinline__ void gld_lds16(const void* g, void* l) {
  __builtin_amdgcn_global_load_lds(
      (const __attribute__((address_space(1))) void*)g,
      (__attribute__((address_space(3))) void*)l, 16, 0, 0);
}

// ---------------- fp32 -> bf16 convert: x and wv ----------------
__global__ void k_cvt2(const float* __restrict__ x, const float* __restrict__ wv,
                       unsigned short* __restrict__ xb, unsigned short* __restrict__ wvb) {
  const int nx = MM*DD/4, nw = DD*DD/4;
  const int ntot = nx + nw;
  int i = blockIdx.x * blockDim.x + threadIdx.x;
  int stride = gridDim.x * blockDim.x;
  for (; i < ntot; i += stride) {
    const float* s; unsigned short* d; int j;
    if (i < nx) { s = x;  d = xb;  j = i; }
    else        { s = wv; d = wvb; j = i - nx; }
    float4 v = reinterpret_cast<const float4*>(s)[j];
    ushort4 o;
    o.x = f2b(v.x); o.y = f2b(v.y); o.z = f2b(v.z); o.w = f2b(v.w);
    reinterpret_cast<ushort4*>(d)[j] = o;
  }
}

// ---------------- transpose-convert: wq, wk (fp32 [o][d]) -> bf16 [d][o] ----------------
__launch_bounds__(256)
__global__ void k_cvtT(const float* __restrict__ wq, const float* __restrict__ wk,
                       unsigned short* __restrict__ wqT, unsigned short* __restrict__ wkT) {
  __shared__ unsigned short tile[64][72];   // [d_local][o_local], padded
  const float* src = blockIdx.z ? wk : wq;
  unsigned short* dst = blockIdx.z ? wkT : wqT;
  const int o0 = blockIdx.x * 64, d0 = blockIdx.y * 64;
  const int tid = threadIdx.x;
  const int r = tid >> 2;            // 0..63
  const int c = (tid & 3) * 16;      // 0,16,32,48
  #pragma unroll
  for (int j = 0; j < 16; j += 4) {
    float4 v = *reinterpret_cast<const float4*>(&src[(size_t)(o0 + r) * DD + d0 + c + j]);
    tile[c + j + 0][r] = f2b(v.x);
    tile[c + j + 1][r] = f2b(v.y);
    tile[c + j + 2][r] = f2b(v.z);
    tile[c + j + 3][r] = f2b(v.w);
  }
  __syncthreads();
  #pragma unroll
  for (int j = 0; j < 16; j += 8) {
    u16x8 u;
    #pragma unroll
    for (int jj = 0; jj < 8; ++jj) u[jj] = tile[r][c + j + jj];
    *reinterpret_cast<u16x8*>(&dst[(size_t)(d0 + r) * DD + o0 + c + j]) = u;
  }
}

// ---------------- Gt = wkT * wqT^T (64x64 tiles -> 256 blocks) ----------------
// Gt[e][d] = sum_o wk[o][e]*wq[o][d]; BT-GEMM with A=wkT, B=wqT. Same swizzle pair as k_yv.
__launch_bounds__(256)
__global__ void k_g(const unsigned short* __restrict__ wkT,
                    const unsigned short* __restrict__ wqT,
                    unsigned short* __restrict__ Gt) {
  __shared__ __align__(16) unsigned short As[64*64];   // 8 KB
  __shared__ __align__(16) unsigned short Bs[64*64];
  const int tid = threadIdx.x;
  const int l = tid & 63, wid = tid >> 6;
  const int l15 = l & 15, l4 = l >> 4;
  const int wr = (wid >> 1) * 32, wc = (wid & 1) * 32;
  const int m0 = blockIdx.x * 64, n0 = blockIdx.y * 64;

  const int srow = wid * 8 + (l >> 3);          // 0..31 (per 32-row unit)
  const int scol = 8 * ((l & 7) ^ (l >> 3));    // pre-swizzled source col
  const unsigned short* Ap = wkT + (size_t)(m0 + srow) * DD + scol;
  const unsigned short* Bp = wqT + (size_t)(n0 + srow) * DD + scol;
  unsigned short* AsW = &As[wid * 512];
  unsigned short* BsW = &Bs[wid * 512];

  f32x4 acc[2][2] = {};

  for (int k0 = 0; k0 < DD; k0 += 64) {
    __syncthreads();
    #pragma unroll
    for (int u = 0; u < 2; ++u) {
      gld_lds16(Ap + (size_t)u*32*DD + k0, AsW + u*2048);
      gld_lds16(Bp + (size_t)u*32*DD + k0, BsW + u*2048);
    }
    __syncthreads();
    #pragma unroll
    for (int kk = 0; kk < 2; ++kk) {
      bf16x8 af[2], bfr[2];
      #pragma unroll
      for (int mi = 0; mi < 2; ++mi) {
        int ro = wr + mi*16 + l15;
        int off = ro*128 + ((kk*64 + l4*16) ^ ((ro & 7) << 4));
        af[mi] = *reinterpret_cast<const bf16x8*>((const char*)As + off);
      }
      #pragma unroll
      for (int ni = 0; ni < 2; ++ni) {
        int ro = wc + ni*16 + l15;
        int off = ro*128 + ((kk*64 + l4*16) ^ ((ro & 7) << 4));
        bfr[ni] = *reinterpret_cast<const bf16x8*>((const char*)Bs + off);
      }
      #pragma unroll
      for (int mi = 0; mi < 2; ++mi)
        #pragma unroll
        for (int ni = 0; ni < 2; ++ni)
          acc[mi][ni] = __builtin_amdgcn_mfma_f32_16x16x32_bf16(af[mi], bfr[ni], acc[mi][ni], 0, 0, 0);
    }
  }

  #pragma unroll
  for (int mi = 0; mi < 2; ++mi)
    #pragma unroll
    for (int ni = 0; ni < 2; ++ni)
      #pragma unroll
      for (int r = 0; r < 4; ++r) {
        int row = wr + mi*16 + l4*4 + r;
        int col = wc + ni*16 + l15;
        Gt[(size_t)(m0 + row) * DD + n0 + col] = f2b(acc[mi][ni][r]);
      }
}

// ---------------- Y = X * Gt^T (z=0), Vt = (X * Wv^T)^T (z=1) ----------------
// r7-proven 2-phase 128x128 BK=64 structure, conflict-free swizzle.
__launch_bounds__(256)
__global__ void k_yv(const unsigned short* __restrict__ xb,
                     const unsigned short* __restrict__ Gtb,
                     const unsigned short* __restrict__ wvb,
                     unsigned short* __restrict__ Y,
                     unsigned short* __restrict__ Vt) {
  __shared__ __align__(16) unsigned short As[128*64];   // 16 KB
  __shared__ __align__(16) unsigned short Bs[128*64];
  const int tid = threadIdx.x;
  const int l = tid & 63, wid = tid >> 6;
  const int z = blockIdx.z;
  const unsigned short* W = z ? wvb : Gtb;
  const long m0 = (long)blockIdx.x * 128;
  const long n0 = (long)blockIdx.y * 128;
  const int l15 = l & 15, l4 = l >> 4;
  const int wr = (wid >> 1) * 64, wc = (wid & 1) * 64;

  const int srow = wid * 8 + (l >> 3);
  const int scol = 8 * ((l & 7) ^ (l >> 3));
  const unsigned short* Ap = xb + (m0 + srow) * DD + scol;
  const unsigned short* Wp = W  + (n0 + srow) * DD + scol;
  unsigned short* AsW = &As[wid * 512];
  unsigned short* BsW = &Bs[wid * 512];

  f32x4 acc[4][4] = {};

  for (int k0 = 0; k0 < DD; k0 += 64) {
    __syncthreads();
    #pragma unroll
    for (int u = 0; u < 4; ++u) {
      gld_lds16(Ap + (size_t)u*32*DD + k0, AsW + u*2048);
      gld_lds16(Wp + (size_t)u*32*DD + k0, BsW + u*2048);
    }
    __syncthreads();
    #pragma unroll
    for (int kk = 0; kk < 2; ++kk) {
      bf16x8 af[4], bfr[4];
      #pragma unroll
      for (int mi = 0; mi < 4; ++mi) {
        int ro = wr + mi*16 + l15;
        int off = ro*128 + ((kk*64 + l4*16) ^ ((ro & 7) << 4));
        af[mi] = *reinterpret_cast<const bf16x8*>((const char*)As + off);
      }
      #pragma unroll
      for (int ni = 0; ni < 4; ++ni) {
        int ro = wc + ni*16 + l15;
        int off = ro*128 + ((kk*64 + l4*16) ^ ((ro & 7) << 4));
        bfr[ni] = *reinterpret_cast<const bf16x8*>((const char*)Bs + off);
      }
      #pragma unroll
      for (int mi = 0; mi < 4; ++mi)
        #pragma unroll
        for (int ni = 0; ni < 4; ++ni)
          acc[mi][ni] = __builtin_amdgcn_mfma_f32_16x16x32_bf16(af[mi], bfr[ni], acc[mi][ni], 0, 0, 0);
    }
  }

  if (z == 0) {
    #pragma unroll
    for (int mi = 0; mi < 4; ++mi)
      #pragma unroll
      for (int ni = 0; ni < 4; ++ni)
        #pragma unroll
        for (int r = 0; r < 4; ++r) {
          long row = m0 + wr + mi*16 + l4*4 + r;
          long col = n0 + wc + ni*16 + l15;
          Y[row * DD + col] = f2b(acc[mi][ni][r]);
        }
  } else {
    #pragma unroll
    for (int mi = 0; mi < 4; ++mi)
      #pragma unroll
      for (int ni = 0; ni < 4; ++ni)
        #pragma unroll
        for (int r = 0; r < 4; ++r) {
          long row = m0 + wr + mi*16 + l4*4 + r;
          long col = n0 + wc + ni*16 + l15;
          long b = row >> 11, t = row & (TT - 1);
          Vt[(b * DD + col) * TT + t] = f2b(acc[mi][ni][r]);   // Vt[b][d][t]
        }
  }
}

// ---------------- S = scale * Y X^T (causal tiles), BK=64 + swizzle ----------------
__launch_bounds__(256)
__global__ void k_scores(const unsigned short* __restrict__ Yb,
                         const unsigned short* __restrict__ xb,
                         unsigned short* __restrict__ S) {
  __shared__ __align__(16) unsigned short As[128*64];
  __shared__ __align__(16) unsigned short Bs[128*64];
  const int tid = threadIdx.x;
  const int l = tid & 63, wid = tid >> 6;
  const int l15 = l & 15, l4 = l >> 4;
  const int wr = (wid >> 1) * 64, wc = (wid & 1) * 64;

  const int bid = blockIdx.x;
  const int swz = (bid & 7) * 68 + (bid >> 3);   // bijective XCD swizzle, 544 = 8*68
  const int b = swz / 136;
  int t = swz % 136;
  int qi = 0;
  while ((qi + 1) * (qi + 2) / 2 <= t) qi++;
  const int ki = t - qi * (qi + 1) / 2;

  const size_t arow0 = (size_t)b * TT + qi * 128;
  const size_t brow0 = (size_t)b * TT + ki * 128;

  const int srow = wid * 8 + (l >> 3);
  const int scol = 8 * ((l & 7) ^ (l >> 3));
  const unsigned short* Ap = Yb + (arow0 + srow) * DD + scol;
  const unsigned short* Bp = xb + (brow0 + srow) * DD + scol;
  unsigned short* AsW = &As[wid * 512];
  unsigned short* BsW = &Bs[wid * 512];

  f32x4 acc[4][4] = {};

  for (int k0 = 0; k0 < DD; k0 += 64) {
    __syncthreads();
    #pragma unroll
    for (int u = 0; u < 4; ++u) {
      gld_lds16(Ap + (size_t)u*32*DD + k0, AsW + u*2048);
      gld_lds16(Bp + (size_t)u*32*DD + k0, BsW + u*2048);
    }
    __syncthreads();
    #pragma unroll
    for (int kk = 0; kk < 2; ++kk) {
      bf16x8 af[4], bfr[4];
      #pragma unroll
      for (int mi = 0; mi < 4; ++mi) {
        int ro = wr + mi*16 + l15;
        int off = ro*128 + ((kk*64 + l4*16) ^ ((ro & 7) << 4));
        af[mi] = *reinterpret_cast<const bf16x8*>((const char*)As + off);
      }
      #pragma unroll
      for (int ni = 0; ni < 4; ++ni) {
        int ro = wc + ni*16 + l15;
        int off = ro*128 + ((kk*64 + l4*16) ^ ((ro & 7) << 4));
        bfr[ni] = *reinterpret_cast<const bf16x8*>((const char*)Bs + off);
      }
      #pragma unroll
      for (int mi = 0; mi < 4; ++mi)
        #pragma unroll
        for (int ni = 0; ni < 4; ++ni)
          acc[mi][ni] = __builtin_amdgcn_mfma_f32_16x16x32_bf16(af[mi], bfr[ni], acc[mi][ni], 0, 0, 0);
    }
  }

  const float scale = 0.03125f;
  #pragma unroll
  for (int mi = 0; mi < 4; ++mi)
    #pragma unroll
    for (int ni = 0; ni < 4; ++ni)
      #pragma unroll
      for (int r = 0; r < 4; ++r) {
        int row = wr + mi*16 + l4*4 + r;
        int col = wc + ni*16 + l15;
        int gq = qi*128 + row, gk = ki*128 + col;
        float v = (gk > gq) ? -1e30f : acc[mi][ni][r] * scale;
        S[((size_t)b * TT + gq) * TT + gk] = f2b(v);
      }
}

// ---------------- rowwise softmax in place ----------------
__launch_bounds__(256)
__global__ void k_softmax(unsigned short* __restrict__ S, float* __restrict__ rl) {
  const int tid = threadIdx.x;
  const int w = tid >> 6, l = tid & 63;
  const int row = blockIdx.x * 4 + w;
  const int b = row >> 11, q = row & (TT - 1);
  unsigned short* Srow = S + ((size_t)b * TT + q) * TT;
  const int width = ((q >> 7) + 1) << 7;

  float v[4][8];
  bool has[4];
  float mx = -1e30f;
  #pragma unroll
  for (int c = 0; c < 4; ++c) {
    const int off = c * 512 + l * 8;
    has[c] = off < width;
    if (has[c]) {
      u16x8 u = *reinterpret_cast<const u16x8*>(&Srow[off]);
      #pragma unroll
      for (int j = 0; j < 8; ++j) { v[c][j] = b2f(u[j]); mx = fmaxf(mx, v[c][j]); }
    }
  }
  #pragma unroll
  for (int mm = 1; mm < 64; mm <<= 1) mx = fmaxf(mx, __shfl_xor(mx, mm));

  float s = 0.f;
  #pragma unroll
  for (int c = 0; c < 4; ++c) {
    if (has[c]) {
      u16x8 u;
      #pragma unroll
      for (int j = 0; j < 8; ++j) {
        float p = __expf(v[c][j] - mx);
        s += p;
        u[j] = f2b(p);
      }
      *reinterpret_cast<u16x8*>(&Srow[c * 512 + l * 8]) = u;
    }
  }
  #pragma unroll
  for (int mm = 1; mm < 64; mm <<= 1) s += __shfl_xor(s, mm);
  if (l == 0) rl[row] = 1.0f / s;
}

// ---------------- O = (P Vt^T) * rl, BK=64 + swizzle ----------------
__launch_bounds__(256)
__global__ void k_pv(const unsigned short* __restrict__ P,
                     const unsigned short* __restrict__ Vt,
                     const float* __restrict__ rl,
                     float* __restrict__ O) {
  __shared__ __align__(16) unsigned short As[128*64];
  __shared__ __align__(16) unsigned short Bs[128*64];
  const int tid = threadIdx.x;
  const int l = tid & 63, wid = tid >> 6;
  const int l15 = l & 15, l4 = l >> 4;
  const int wr = (wid >> 1) * 64, wc = (wid & 1) * 64;

  const int qi = 15 - (blockIdx.x >> 5);       // heaviest first
  const int di = (blockIdx.x >> 2) & 7;
  const int b  = blockIdx.x & 3;
  const int KEXT = (qi + 1) * 128;

  const int srow = wid * 8 + (l >> 3);
  const int scol = 8 * ((l & 7) ^ (l >> 3));
  const unsigned short* Ap = P  + ((size_t)b * TT + qi * 128 + srow) * TT + scol;
  const unsigned short* Bp = Vt + ((size_t)b * DD + di * 128 + srow) * TT + scol;
  unsigned short* AsW = &As[wid * 512];
  unsigned short* BsW = &Bs[wid * 512];

  f32x4 acc[4][4] = {};

  for (int k0 = 0; k0 < KEXT; k0 += 64) {
    __syncthreads();
    #pragma unroll
    for (int u = 0; u < 4; ++u) {
      gld_lds16(Ap + (size_t)u*32*TT + k0, AsW + u*2048);
      gld_lds16(Bp + (size_t)u*32*TT + k0, BsW + u*2048);
    }
    __syncthreads();
    #pragma unroll
    for (int kk = 0; kk < 2; ++kk) {
      bf16x8 af[4], bfr[4];
      #pragma unroll
      for (int mi = 0; mi < 4; ++mi) {
        int ro = wr + mi*16 + l15;
        int off = ro*128 + ((kk*64 + l4*16) ^ ((ro & 7) << 4));
        af[mi] = *reinterpret_cast<const bf16x8*>((const char*)As + off);
      }
      #pragma unroll
      for (int ni = 0; ni < 4; ++ni) {
        int ro = wc + ni*16 + l15;
        int off = ro*128 + ((kk*64 + l4*16) ^ ((ro & 7) << 4));
        bfr[ni] = *reinterpret_cast<const bf16x8*>((const char*)Bs + off);
      }
      #pragma unroll
      for (int mi = 0; mi < 4; ++mi)
        #pragma unroll
        for (int ni = 0; ni < 4; ++ni)
          acc[mi][ni] = __builtin_amdgcn_mfma_f32_16x16x32_bf16(af[mi], bfr[ni], acc[mi][ni], 0, 0, 0);
    }
  }

  #pragma unroll
  for (int mi = 0; mi < 4; ++mi)
    #pragma unroll
    for (int ni = 0; ni < 4; ++ni)
      #pragma unroll
      for (int r = 0; r < 4; ++r) {
        int row = wr + mi*16 + l4*4 + r;
        int col = wc + ni*16 + l15;
        size_t q = (size_t)qi * 128 + row;
        O[((size_t)b * TT + q) * DD + di * 128 + col] =
            acc[mi][ni][r] * rl[(size_t)b * TT + q];
      }
}

extern "C" void kernel_launch(void* const* d_in, const int* in_sizes, int n_in,
                              void* d_out, int out_size, void* d_ws, size_t ws_size,
                              hipStream_t stream) {
  const float* x  = (const float*)d_in[0];
  const float* wq = (const float*)d_in[1];
  const float* wk = (const float*)d_in[2];
  const float* wv = (const float*)d_in[3];
  unsigned short* ws  = (unsigned short*)d_ws;
  // Layout (bf16 elems):
  //   [xb: MM*DD][Y: MM*DD][Vt: MM*DD][S: NB*TT*TT][rl: MM floats]
  // wvb/wqT/wkT/Gt alias the S region (all dead before k_scores writes S).
  unsigned short* xb  = ws;
  unsigned short* Y   = xb + (size_t)MM * DD;
  unsigned short* Vt  = Y  + (size_t)MM * DD;
  unsigned short* Sb  = Vt + (size_t)MM * DD;
  unsigned short* wvb = Sb;
  unsigned short* wqT = wvb + (size_t)DD * DD;
  unsigned short* wkT = wqT + (size_t)DD * DD;
  unsigned short* Gt  = wkT + (size_t)DD * DD;
  float* rl = (float*)(Sb + (size_t)NB * TT * TT);
  float* out = (float*)d_out;

  k_cvt2<<<2048, 256, 0, stream>>>(x, wv, xb, wvb);
  k_cvtT<<<dim3(16, 16, 2), 256, 0, stream>>>(wq, wk, wqT, wkT);
  k_g<<<dim3(16, 16), 256, 0, stream>>>(wkT, wqT, Gt);
  k_yv<<<dim3(MM/128, DD/128, 2), 256, 0, stream>>>(xb, Gt, wvb, Y, Vt);
  k_scores<<<544, 256, 0, stream>>>(Y, xb, Sb);
  k_softmax<<<MM/4, 256, 0, stream>>>(Sb, rl);
  k_pv<<<512, 256, 0, stream>>>(Sb, Vt, rl, out);
}